// Round 2
// baseline (3227.828 us; speedup 1.0000x reference)
//
#include <hip/hip_runtime.h>
#include <hip/hip_bf16.h>

typedef __hip_bfloat16 bf16;
typedef unsigned short u16;
typedef u16 u16x8 __attribute__((ext_vector_type(8)));

__device__ __forceinline__ float b2f(u16 u) {
    unsigned v = ((unsigned)u) << 16;
    float f; __builtin_memcpy(&f, &v, 4); return f;
}
__device__ __forceinline__ float sigmoidf_(float x) { return 1.f / (1.f + expf(-x)); }

// dtype-generic 8-element loads (fp32 or bf16 source), fp32 lanes out
__device__ __forceinline__ void load8(const float* __restrict__ p, float* x) {
    float4 a = *reinterpret_cast<const float4*>(p);
    float4 b = *reinterpret_cast<const float4*>(p + 4);
    x[0]=a.x; x[1]=a.y; x[2]=a.z; x[3]=a.w; x[4]=b.x; x[5]=b.y; x[6]=b.z; x[7]=b.w;
}
__device__ __forceinline__ void load8(const bf16* __restrict__ p, float* x) {
    u16x8 u = *reinterpret_cast<const u16x8*>(p);
#pragma unroll
    for (int j = 0; j < 8; ++j) x[j] = b2f(u[j]);
}
__device__ __forceinline__ void store1(float* p, float v) { *p = v; }
__device__ __forceinline__ void store1(bf16* p, float v) { *p = __float2bfloat16(v); }

// ---------------------------------------------------------------------------
// Generic NN GEMM: C[r,n] = sum_k A[r,k]*B[k,n] (+bias). Batched over grid.z.
// Tile 64x64, K-step 32, 256 threads, 4x4 micro-tile, fp32 accumulate.
// EPI 0: out0 <- C
// EPI 1: out0 <- C (prior_delta); out1 <- C + anchor[b,n] (prior_absolute)
// ---------------------------------------------------------------------------
template<int EPI, class TA, class TB, class TO>
__global__ __launch_bounds__(256)
void k_gemm_nn(const TA* __restrict__ A, long long sA, int lda,
               const TB* __restrict__ B, long long sB, int ldb,
               const float* __restrict__ bias,
               TO* __restrict__ out0, long long sO,
               float* __restrict__ out1, const float* __restrict__ anchor,
               int N, int K, int rowsPerB)
{
    __shared__ float As[64][33];
    __shared__ float Bs[32][65];
    const int tid = threadIdx.x;
    const int z = blockIdx.z;
    const int n0 = blockIdx.x * 64;
    const int r0 = blockIdx.y * 64;
    A += z * sA;
    B += z * sB;

    const int lr = tid >> 2, lc = (tid & 3) * 8;   // A loader
    const int br = tid >> 3, bc = (tid & 7) * 8;   // B loader
    const int tx = tid & 15, ty = tid >> 4;

    float acc[4][4] = {};
    for (int k0 = 0; k0 < K; k0 += 32) {
        float xa[8], xb[8];
        load8(A + (long long)(r0 + lr) * lda + (k0 + lc), xa);
        load8(B + (long long)(k0 + br) * ldb + (n0 + bc), xb);
#pragma unroll
        for (int j = 0; j < 8; ++j) As[lr][lc + j] = xa[j];
#pragma unroll
        for (int j = 0; j < 8; ++j) Bs[br][bc + j] = xb[j];
        __syncthreads();
#pragma unroll
        for (int kk = 0; kk < 32; ++kk) {
            float a[4], bb[4];
#pragma unroll
            for (int i = 0; i < 4; ++i) a[i] = As[ty * 4 + i][kk];
#pragma unroll
            for (int j = 0; j < 4; ++j) bb[j] = Bs[kk][tx * 4 + j];
#pragma unroll
            for (int i = 0; i < 4; ++i)
#pragma unroll
                for (int j = 0; j < 4; ++j) acc[i][j] = fmaf(a[i], bb[j], acc[i][j]);
        }
        __syncthreads();
    }
#pragma unroll
    for (int i = 0; i < 4; ++i) {
        const int r = r0 + ty * 4 + i;
#pragma unroll
        for (int j = 0; j < 4; ++j) {
            const int c = n0 + tx * 4 + j;
            float v = acc[i][j];
            if (bias) v += bias[c];
            if constexpr (EPI == 0) {
                store1(out0 + z * sO + (long long)r * N + c, v);
            } else {
                store1(out0 + (long long)r * N + c, v);
                out1[(long long)r * N + c] = v + anchor[(long long)(r / rowsPerB) * 512 + c];
            }
        }
    }
}

// ---------------------------------------------------------------------------
// NT GEMM (attention logits): C[r,n] = scale * sum_k Q[r,k]*Kt[n,k], batched.
// Q,Kt bf16 ws; out fp32.
// ---------------------------------------------------------------------------
__global__ __launch_bounds__(256)
void k_gemm_nt(const bf16* __restrict__ Q, long long sQ,
               const bf16* __restrict__ Kt, long long sK,
               float* __restrict__ out, long long sO,
               int N, int K, float scale)
{
    __shared__ float As[64][33];
    __shared__ float Bs[32][65];
    const int tid = threadIdx.x;
    const int z = blockIdx.z;
    Q += z * sQ; Kt += z * sK;
    const int n0 = blockIdx.x * 64;
    const int r0 = blockIdx.y * 64;
    const int lr = tid >> 2, lc = (tid & 3) * 8;
    const int tx = tid & 15, ty = tid >> 4;

    float acc[4][4] = {};
    for (int k0 = 0; k0 < K; k0 += 32) {
        float xa[8], xb[8];
        load8(Q + (long long)(r0 + lr) * K + (k0 + lc), xa);
        load8(Kt + (long long)(n0 + lr) * K + (k0 + lc), xb);
#pragma unroll
        for (int j = 0; j < 8; ++j) As[lr][lc + j] = xa[j];
#pragma unroll
        for (int j = 0; j < 8; ++j) Bs[lc + j][lr] = xb[j];
        __syncthreads();
#pragma unroll
        for (int kk = 0; kk < 32; ++kk) {
            float a[4], bb[4];
#pragma unroll
            for (int i = 0; i < 4; ++i) a[i] = As[ty * 4 + i][kk];
#pragma unroll
            for (int j = 0; j < 4; ++j) bb[j] = Bs[kk][tx * 4 + j];
#pragma unroll
            for (int i = 0; i < 4; ++i)
#pragma unroll
                for (int j = 0; j < 4; ++j) acc[i][j] = fmaf(a[i], bb[j], acc[i][j]);
        }
        __syncthreads();
    }
#pragma unroll
    for (int i = 0; i < 4; ++i)
#pragma unroll
        for (int j = 0; j < 4; ++j)
            out[z * sO + (long long)(r0 + ty * 4 + i) * N + (n0 + tx * 4 + j)] =
                scale * acc[i][j];
}

// ---------------------------------------------------------------------------
// In-place row softmax over rows of 2048 fp32 elements. One block per row.
// ---------------------------------------------------------------------------
__global__ __launch_bounds__(256)
void k_softmax(float* __restrict__ attn)
{
    __shared__ float redm[4], reds[4];
    const long long row = blockIdx.x;
    float* p = attn + row * 2048;
    const int tid = threadIdx.x;

    float x[8];
    load8(p + tid * 8, x);
    float mx = -1e30f;
#pragma unroll
    for (int j = 0; j < 8; ++j) mx = fmaxf(mx, x[j]);
#pragma unroll
    for (int off = 32; off; off >>= 1) mx = fmaxf(mx, __shfl_xor(mx, off));
    if ((tid & 63) == 0) redm[tid >> 6] = mx;
    __syncthreads();
    mx = fmaxf(fmaxf(redm[0], redm[1]), fmaxf(redm[2], redm[3]));

    float s = 0.f;
#pragma unroll
    for (int j = 0; j < 8; ++j) { x[j] = expf(x[j] - mx); s += x[j]; }
#pragma unroll
    for (int off = 32; off; off >>= 1) s += __shfl_xor(s, off);
    if ((tid & 63) == 0) reds[tid >> 6] = s;
    __syncthreads();
    const float inv = 1.f / (reds[0] + reds[1] + reds[2] + reds[3]);

    float4 o0 = make_float4(x[0]*inv, x[1]*inv, x[2]*inv, x[3]*inv);
    float4 o1 = make_float4(x[4]*inv, x[5]*inv, x[6]*inv, x[7]*inv);
    *reinterpret_cast<float4*>(p + tid * 8)     = o0;
    *reinterpret_cast<float4*>(p + tid * 8 + 4) = o1;
}

// ---------------------------------------------------------------------------
// Concat-gather GEMM for the gate MLPs (all fp32): A cols [0,2048) -> 4 sources
// of 512 each. mode2=1: source 2 is anchor[B,512] broadcast over S (row>>11).
// Epilogue: relu(C + bias) -> f32 hidden.  R=16384, N=512, K=2048 fixed.
// ---------------------------------------------------------------------------
__global__ __launch_bounds__(256)
void k_gemm_cat(const float* __restrict__ s0, const float* __restrict__ s1,
                const float* __restrict__ s2, const float* __restrict__ s3,
                int mode2,
                const float* __restrict__ B, const float* __restrict__ bias,
                float* __restrict__ outf)
{
    __shared__ float As[64][33];
    __shared__ float Bs[32][65];
    const int tid = threadIdx.x;
    const int n0 = blockIdx.x * 64;
    const int r0 = blockIdx.y * 64;
    const int lr = tid >> 2, lc = (tid & 3) * 8;
    const int br = tid >> 3, bc = (tid & 7) * 8;
    const int tx = tid & 15, ty = tid >> 4;

    float acc[4][4] = {};
    for (int k0 = 0; k0 < 2048; k0 += 32) {
        const int srcIdx = k0 >> 9;
        const int kloc = (k0 & 511) + lc;
        const float* sp = (srcIdx == 0) ? s0 : (srcIdx == 1) ? s1 : (srcIdx == 2) ? s2 : s3;
        const int r = r0 + lr;
        long long rowoff;
        if (srcIdx == 2 && mode2) rowoff = (long long)(r >> 11) * 512;
        else                      rowoff = (long long)r * 512;
        float xa[8], xb[8];
        load8(sp + rowoff + kloc, xa);
        load8(B + (long long)(k0 + br) * 512 + (n0 + bc), xb);
#pragma unroll
        for (int j = 0; j < 8; ++j) As[lr][lc + j] = xa[j];
#pragma unroll
        for (int j = 0; j < 8; ++j) Bs[br][bc + j] = xb[j];
        __syncthreads();
#pragma unroll
        for (int kk = 0; kk < 32; ++kk) {
            float a[4], bb[4];
#pragma unroll
            for (int i = 0; i < 4; ++i) a[i] = As[ty * 4 + i][kk];
#pragma unroll
            for (int j = 0; j < 4; ++j) bb[j] = Bs[kk][tx * 4 + j];
#pragma unroll
            for (int i = 0; i < 4; ++i)
#pragma unroll
                for (int j = 0; j < 4; ++j) acc[i][j] = fmaf(a[i], bb[j], acc[i][j]);
        }
        __syncthreads();
    }
#pragma unroll
    for (int i = 0; i < 4; ++i) {
        const int r = r0 + ty * 4 + i;
#pragma unroll
        for (int j = 0; j < 4; ++j) {
            const int c = n0 + tx * 4 + j;
            float v = acc[i][j] + bias[c];
            outf[(long long)r * 512 + c] = fmaxf(v, 0.f);
        }
    }
}

// ---------------------------------------------------------------------------
// Gate GEMV: logit = hidden[row,:512] . w2 + b2.  One wave per row.
// ---------------------------------------------------------------------------
__global__ __launch_bounds__(64)
void k_gate(const float* __restrict__ hidden, const float* __restrict__ w2,
            const float* __restrict__ b2,
            float* __restrict__ outLogit, float* __restrict__ outGate,
            float scl, float add)
{
    const long long row = blockIdx.x;
    const int lane = threadIdx.x;
    float s = 0.f;
#pragma unroll
    for (int j = 0; j < 8; ++j) {
        int idx = lane + j * 64;
        s += hidden[row * 512 + idx] * w2[idx];
    }
#pragma unroll
    for (int off = 32; off; off >>= 1) s += __shfl_xor(s, off);
    if (lane == 0) {
        float logit = s + b2[0];
        if (outLogit) outLogit[row] = logit;
        outGate[row] = sigmoidf_(logit * scl + add);
    }
}

// ---------------------------------------------------------------------------
// Slerp: one wave per row (512 elems, 8/lane). a=prior_absolute, b=local.
// cand <- slerp(a,b,t);  cdelta <- cand - anchor[b-row].  All fp32.
// ---------------------------------------------------------------------------
__global__ __launch_bounds__(64)
void k_slerp(const float* __restrict__ prior, const float* __restrict__ localv,
             const float* __restrict__ mixv, const float* __restrict__ anchor,
             float* __restrict__ cand, float* __restrict__ cdelta)
{
    const int row = blockIdx.x;
    const int lane = threadIdx.x;
    const long long base = (long long)row * 512 + lane * 8;
    const long long abase = (long long)(row >> 11) * 512 + lane * 8;

    float a[8], b[8];
    load8(prior + base, a);
    load8(localv + base, b);
    float sa = 0.f, sb = 0.f, sab = 0.f;
#pragma unroll
    for (int j = 0; j < 8; ++j) {
        sa = fmaf(a[j], a[j], sa); sb = fmaf(b[j], b[j], sb); sab = fmaf(a[j], b[j], sab);
    }
#pragma unroll
    for (int off = 1; off < 64; off <<= 1) {
        sa += __shfl_xor(sa, off); sb += __shfl_xor(sb, off); sab += __shfl_xor(sab, off);
    }
    const float eps = 1e-6f;
    float na = fmaxf(sqrtf(sa), eps), nb = fmaxf(sqrtf(sb), eps);
    float dot = sab / (na * nb);
    dot = fminf(fmaxf(dot, -1.f + eps), 1.f - eps);
    float omega = acosf(dot);
    float so = fmaxf(sinf(omega), eps);
    float t = mixv[row];
    t = fminf(fmaxf(t, 0.f), 1.f);
    float sca = sinf((1.f - t) * omega) / so;
    float scb = sinf(t * omega) / so;

    float an[8];
    load8(anchor + abase, an);
    float c0[8], d0[8];
#pragma unroll
    for (int j = 0; j < 8; ++j) {
        c0[j] = sca * a[j] + scb * b[j];
        d0[j] = c0[j] - an[j];
    }
    *reinterpret_cast<float4*>(cand + base)       = make_float4(c0[0], c0[1], c0[2], c0[3]);
    *reinterpret_cast<float4*>(cand + base + 4)   = make_float4(c0[4], c0[5], c0[6], c0[7]);
    *reinterpret_cast<float4*>(cdelta + base)     = make_float4(d0[0], d0[1], d0[2], d0[3]);
    *reinterpret_cast<float4*>(cdelta + base + 4) = make_float4(d0[4], d0[5], d0[6], d0[7]);
}

// ---------------------------------------------------------------------------
extern "C" void kernel_launch(void* const* d_in, const int* in_sizes, int n_in,
                              void* d_out, int out_size, void* d_ws, size_t ws_size,
                              hipStream_t stream)
{
    const float* query  = (const float*)d_in[0];
    const float* anchor = (const float*)d_in[1];
    const float* gmem   = (const float*)d_in[2];
    const float* local_ = (const float*)d_in[3];
    const float* style  = (const float*)d_in[4];
    const float* Wq = (const float*)d_in[5];   const float* bq = (const float*)d_in[6];
    const float* Wk = (const float*)d_in[7];   const float* bk = (const float*)d_in[8];
    const float* Wv = (const float*)d_in[9];   const float* bv = (const float*)d_in[10];
    const float* Wo = (const float*)d_in[11];  const float* bo = (const float*)d_in[12];
    const float* Wm1 = (const float*)d_in[13]; const float* bm1 = (const float*)d_in[14];
    const float* Wm2 = (const float*)d_in[15]; const float* bm2 = (const float*)d_in[16];
    const float* Wg1 = (const float*)d_in[17]; const float* bg1 = (const float*)d_in[18];
    const float* Wg2 = (const float*)d_in[19]; const float* bg2 = (const float*)d_in[20];

    float* out = (float*)d_out;
    const long long SH = 16384LL * 512;          // B*S*H = 8,388,608
    float* o_attn = out;                         // [B,S,M] 33,554,432
    float* o_pd   = out + 33554432LL;            // prior_delta
    float* o_pa   = o_pd + SH;                   // prior_absolute
    float* o_mix  = o_pa + SH;                   // mix [16384]
    float* o_ca   = o_mix + 16384;               // candidate_absolute
    float* o_cd   = o_ca + SH;                   // candidate_delta
    float* o_vl   = o_cd + SH;                   // variation_logit [16384]
    float* o_vg   = o_vl + 16384;                // variation_gate [16384]

    bf16* wq_  = (bf16*)d_ws;                    // q  [16384,512] bf16
    bf16* wk_  = wq_ + SH;                       // k
    bf16* wv_  = wk_ + SH;                       // v
    bf16* wctx = wv_ + SH;                       // attn@v
    float* whid = (float*)(wctx + SH);           // hidden [16384,512] f32

    const dim3 blk(256);
    const float invSqrtH = 0.04419417382415922f; // 1/sqrt(512)

    // q,k,v projections: [16384,512] x [512,512] fp32 -> bf16 ws
    k_gemm_nn<0, float, float, bf16><<<dim3(8, 256, 1), blk, 0, stream>>>(
        query, 0, 512, Wq, 0, 512, bq, wq_, 0, nullptr, nullptr, 512, 512, 2048);
    k_gemm_nn<0, float, float, bf16><<<dim3(8, 256, 1), blk, 0, stream>>>(
        gmem, 0, 512, Wk, 0, 512, bk, wk_, 0, nullptr, nullptr, 512, 512, 2048);
    k_gemm_nn<0, float, float, bf16><<<dim3(8, 256, 1), blk, 0, stream>>>(
        gmem, 0, 512, Wv, 0, 512, bv, wv_, 0, nullptr, nullptr, 512, 512, 2048);
    // attention logits: per batch [2048,512] x [512,2048]^T -> out slot0 (fp32)
    k_gemm_nt<<<dim3(32, 32, 8), blk, 0, stream>>>(wq_, 2048LL * 512, wk_, 2048LL * 512,
                                                   o_attn, 2048LL * 2048, 2048, 512, invSqrtH);
    // softmax in-place
    k_softmax<<<16384, 256, 0, stream>>>(o_attn);
    // attn @ v: per batch [2048,2048] x [2048,512] -> ctx (bf16 ws)
    k_gemm_nn<0, float, bf16, bf16><<<dim3(8, 32, 8), blk, 0, stream>>>(
        o_attn, 2048LL * 2048, 2048, wv_, 2048LL * 512, 512, nullptr,
        wctx, 2048LL * 512, nullptr, nullptr, 512, 2048, 2048);
    // Wo projection + prior epilogue (fp32 outputs)
    k_gemm_nn<1, bf16, float, float><<<dim3(8, 256, 1), blk, 0, stream>>>(
        wctx, 0, 512, Wo, 0, 512, bo, o_pd, 0, o_pa, anchor, 512, 512, 2048);
    // mix gate MLP
    k_gemm_cat<<<dim3(8, 256, 1), blk, 0, stream>>>(query, o_pa, local_, style, 0, Wm1, bm1, whid);
    k_gate<<<16384, 64, 0, stream>>>(whid, Wm2, bm2, nullptr, o_mix, 1.0f, -0.25f);
    // slerp -> candidate_absolute, candidate_delta
    k_slerp<<<16384, 64, 0, stream>>>(o_pa, local_, o_mix, anchor, o_ca, o_cd);
    // variation gate MLP (src2 = anchor broadcast)
    k_gemm_cat<<<dim3(8, 256, 1), blk, 0, stream>>>(query, o_ca, anchor, style, 1, Wg1, bg1, whid);
    k_gate<<<16384, 64, 0, stream>>>(whid, Wg2, bg2, o_vl, o_vg, 1.0f, -1.0f);
}

// Round 3
// 667.048 us; speedup vs baseline: 4.8390x; 4.8390x over previous
//
#include <hip/hip_runtime.h>
#include <hip/hip_bf16.h>

typedef __hip_bfloat16 bf16;
typedef unsigned short u16;
typedef u16 u16x8 __attribute__((ext_vector_type(8)));
typedef short bf16x8 __attribute__((ext_vector_type(8)));
typedef float f32x4 __attribute__((ext_vector_type(4)));

__device__ __forceinline__ float sigmoidf_(float x) { return 1.f / (1.f + expf(-x)); }
__device__ __forceinline__ short f2s(float f) {
    bf16 h = __float2bfloat16(f);
    short s; __builtin_memcpy(&s, &h, 2); return s;
}
// stage 16 contiguous elements -> bf16 bit patterns
__device__ __forceinline__ void g2b16(const float* __restrict__ p, short* d) {
#pragma unroll
    for (int q = 0; q < 4; ++q) {
        float4 v = *reinterpret_cast<const float4*>(p + 4 * q);
        d[4*q+0] = f2s(v.x); d[4*q+1] = f2s(v.y); d[4*q+2] = f2s(v.z); d[4*q+3] = f2s(v.w);
    }
}
__device__ __forceinline__ void g2b16(const bf16* __restrict__ p, short* d) {
    *reinterpret_cast<u16x8*>(d)     = *reinterpret_cast<const u16x8*>(p);
    *reinterpret_cast<u16x8*>(d + 8) = *reinterpret_cast<const u16x8*>(p + 8);
}
__device__ __forceinline__ short ldb1(const float* __restrict__ p) { return f2s(*p); }
__device__ __forceinline__ short ldb1(const bf16* __restrict__ p) {
    short s; __builtin_memcpy(&s, p, 2); return s;
}
__device__ __forceinline__ void load8f(const float* __restrict__ p, float* x) {
    float4 a = *reinterpret_cast<const float4*>(p);
    float4 b = *reinterpret_cast<const float4*>(p + 4);
    x[0]=a.x; x[1]=a.y; x[2]=a.z; x[3]=a.w; x[4]=b.x; x[5]=b.y; x[6]=b.z; x[7]=b.w;
}

// ---------------------------------------------------------------------------
// MFMA GEMM: C[m,n] = scale * sum_k A[m,k]*B[.,.] (+bias), batched over z.
// Tile 128x128, BK=32, 256 threads (4 waves, 2x2 of 64x64), 16x16x32 bf16 MFMA.
// BMODE 0: B row-major [k][n] (lda=ldb applies); BMODE 1: B stored [n][k].
// EPI 0: bf16 out0 (+bias if given)
// EPI 1: f32 out0 (scale applied)
// EPI 2: f32 out0 = v+bias (prior_delta); f32 out1 = out0 + anchor[m>>11, n]
// ---------------------------------------------------------------------------
template<int EPI, int BMODE, class TA, class TB>
__global__ __launch_bounds__(256)
void k_mfma(const TA* __restrict__ A, long long sA, int lda,
            const TB* __restrict__ B, long long sB, int ldb,
            const float* __restrict__ bias,
            void* __restrict__ out0, long long sO,
            float* __restrict__ out1, const float* __restrict__ anchor,
            int N, int K, float scale)
{
    __shared__ short As[128 * 40];
    __shared__ short Bs[128 * 40];
    const int tid = threadIdx.x;
    const int z = blockIdx.z;
    const int n0 = blockIdx.x * 128, m0 = blockIdx.y * 128;
    A += (long long)z * sA;
    B += (long long)z * sB;

    const int sr = tid & 127;            // staging row (m_local / n_local)
    const int sk = (tid >> 7) * 16;      // staging k-chunk base
    const int lane = tid & 63;
    const int w = tid >> 6;
    const int wm = (w >> 1) * 64, wn = (w & 1) * 64;
    const int fr = lane & 15, fq = lane >> 4;

    f32x4 acc[4][4];
#pragma unroll
    for (int i = 0; i < 4; ++i)
#pragma unroll
        for (int j = 0; j < 4; ++j) acc[i][j] = f32x4{0.f, 0.f, 0.f, 0.f};

    for (int k0 = 0; k0 < K; k0 += 32) {
        short a16[16], b16[16];
        g2b16(A + (long long)(m0 + sr) * lda + (k0 + sk), a16);
        if constexpr (BMODE == 0) {
#pragma unroll
            for (int q = 0; q < 16; ++q)
                b16[q] = ldb1(B + (long long)(k0 + sk + q) * ldb + (n0 + sr));
        } else {
            g2b16(B + (long long)(n0 + sr) * ldb + (k0 + sk), b16);
        }
        *reinterpret_cast<bf16x8*>(&As[sr * 40 + sk])     = *reinterpret_cast<bf16x8*>(&a16[0]);
        *reinterpret_cast<bf16x8*>(&As[sr * 40 + sk + 8]) = *reinterpret_cast<bf16x8*>(&a16[8]);
        *reinterpret_cast<bf16x8*>(&Bs[sr * 40 + sk])     = *reinterpret_cast<bf16x8*>(&b16[0]);
        *reinterpret_cast<bf16x8*>(&Bs[sr * 40 + sk + 8]) = *reinterpret_cast<bf16x8*>(&b16[8]);
        __syncthreads();

        bf16x8 af[4], bf_[4];
#pragma unroll
        for (int i = 0; i < 4; ++i)
            af[i] = *reinterpret_cast<const bf16x8*>(&As[(wm + i * 16 + fr) * 40 + fq * 8]);
#pragma unroll
        for (int j = 0; j < 4; ++j)
            bf_[j] = *reinterpret_cast<const bf16x8*>(&Bs[(wn + j * 16 + fr) * 40 + fq * 8]);
#pragma unroll
        for (int i = 0; i < 4; ++i)
#pragma unroll
            for (int j = 0; j < 4; ++j)
                acc[i][j] = __builtin_amdgcn_mfma_f32_16x16x32_bf16(af[i], bf_[j], acc[i][j], 0, 0, 0);
        __syncthreads();
    }

#pragma unroll
    for (int j = 0; j < 4; ++j) {
        const int col = n0 + wn + j * 16 + fr;
        const float bv = bias ? bias[col] : 0.f;
#pragma unroll
        for (int i = 0; i < 4; ++i) {
#pragma unroll
            for (int r = 0; r < 4; ++r) {
                const long long row = m0 + wm + i * 16 + fq * 4 + r;
                float v = acc[i][j][r] * scale + bv;
                if constexpr (EPI == 0) {
                    ((bf16*)out0)[(long long)z * sO + row * N + col] = __float2bfloat16(v);
                } else if constexpr (EPI == 1) {
                    ((float*)out0)[(long long)z * sO + row * N + col] = v;
                } else {
                    ((float*)out0)[row * N + col] = v;
                    out1[row * N + col] = v + anchor[(row >> 11) * 512 + col];
                }
            }
        }
    }
}

// ---------------------------------------------------------------------------
// Concat-gather MFMA GEMM for gate MLPs: A cols [0,2048) from 4 fp32 sources of
// 512 each (mode2=1: src2 = anchor[B,512] broadcast over S). B fp32 [2048][512].
// Epilogue: relu(C+bias) -> f32 hidden.  M=16384, N=512, K=2048.
// ---------------------------------------------------------------------------
__global__ __launch_bounds__(256)
void k_cat(const float* __restrict__ s0, const float* __restrict__ s1,
           const float* __restrict__ s2, const float* __restrict__ s3,
           int mode2,
           const float* __restrict__ B, const float* __restrict__ bias,
           float* __restrict__ outf)
{
    __shared__ short As[128 * 40];
    __shared__ short Bs[128 * 40];
    const int tid = threadIdx.x;
    const int n0 = blockIdx.x * 128, m0 = blockIdx.y * 128;
    const int sr = tid & 127;
    const int sk = (tid >> 7) * 16;
    const int lane = tid & 63;
    const int w = tid >> 6;
    const int wm = (w >> 1) * 64, wn = (w & 1) * 64;
    const int fr = lane & 15, fq = lane >> 4;

    f32x4 acc[4][4];
#pragma unroll
    for (int i = 0; i < 4; ++i)
#pragma unroll
        for (int j = 0; j < 4; ++j) acc[i][j] = f32x4{0.f, 0.f, 0.f, 0.f};

    for (int k0 = 0; k0 < 2048; k0 += 32) {
        short a16[16], b16[16];
        const int kg = k0 + sk;
        const int srcIdx = kg >> 9;
        const int kloc = kg & 511;
        const float* sp = (srcIdx == 0) ? s0 : (srcIdx == 1) ? s1 : (srcIdx == 2) ? s2 : s3;
        const int r = m0 + sr;
        const long long rowoff = (srcIdx == 2 && mode2) ? ((long long)(r >> 11) * 512)
                                                        : ((long long)r * 512);
        g2b16(sp + rowoff + kloc, a16);
#pragma unroll
        for (int q = 0; q < 16; ++q)
            b16[q] = f2s(B[(long long)(kg + q) * 512 + (n0 + sr)]);

        *reinterpret_cast<bf16x8*>(&As[sr * 40 + sk])     = *reinterpret_cast<bf16x8*>(&a16[0]);
        *reinterpret_cast<bf16x8*>(&As[sr * 40 + sk + 8]) = *reinterpret_cast<bf16x8*>(&a16[8]);
        *reinterpret_cast<bf16x8*>(&Bs[sr * 40 + sk])     = *reinterpret_cast<bf16x8*>(&b16[0]);
        *reinterpret_cast<bf16x8*>(&Bs[sr * 40 + sk + 8]) = *reinterpret_cast<bf16x8*>(&b16[8]);
        __syncthreads();

        bf16x8 af[4], bf_[4];
#pragma unroll
        for (int i = 0; i < 4; ++i)
            af[i] = *reinterpret_cast<const bf16x8*>(&As[(wm + i * 16 + fr) * 40 + fq * 8]);
#pragma unroll
        for (int j = 0; j < 4; ++j)
            bf_[j] = *reinterpret_cast<const bf16x8*>(&Bs[(wn + j * 16 + fr) * 40 + fq * 8]);
#pragma unroll
        for (int i = 0; i < 4; ++i)
#pragma unroll
            for (int j = 0; j < 4; ++j)
                acc[i][j] = __builtin_amdgcn_mfma_f32_16x16x32_bf16(af[i], bf_[j], acc[i][j], 0, 0, 0);
        __syncthreads();
    }

#pragma unroll
    for (int j = 0; j < 4; ++j) {
        const int col = n0 + wn + j * 16 + fr;
        const float bv = bias[col];
#pragma unroll
        for (int i = 0; i < 4; ++i) {
#pragma unroll
            for (int r = 0; r < 4; ++r) {
                const long long row = m0 + wm + i * 16 + fq * 4 + r;
                outf[row * 512 + col] = fmaxf(acc[i][j][r] + bv, 0.f);
            }
        }
    }
}

// ---------------------------------------------------------------------------
// In-place row softmax over rows of 2048 fp32. One block per row.
// ---------------------------------------------------------------------------
__global__ __launch_bounds__(256)
void k_softmax(float* __restrict__ attn)
{
    __shared__ float redm[4], reds[4];
    const long long row = blockIdx.x;
    float* p = attn + row * 2048;
    const int tid = threadIdx.x;

    float x[8];
    load8f(p + tid * 8, x);
    float mx = -1e30f;
#pragma unroll
    for (int j = 0; j < 8; ++j) mx = fmaxf(mx, x[j]);
#pragma unroll
    for (int off = 32; off; off >>= 1) mx = fmaxf(mx, __shfl_xor(mx, off));
    if ((tid & 63) == 0) redm[tid >> 6] = mx;
    __syncthreads();
    mx = fmaxf(fmaxf(redm[0], redm[1]), fmaxf(redm[2], redm[3]));

    float s = 0.f;
#pragma unroll
    for (int j = 0; j < 8; ++j) { x[j] = expf(x[j] - mx); s += x[j]; }
#pragma unroll
    for (int off = 32; off; off >>= 1) s += __shfl_xor(s, off);
    if ((tid & 63) == 0) reds[tid >> 6] = s;
    __syncthreads();
    const float inv = 1.f / (reds[0] + reds[1] + reds[2] + reds[3]);

    *reinterpret_cast<float4*>(p + tid * 8)     = make_float4(x[0]*inv, x[1]*inv, x[2]*inv, x[3]*inv);
    *reinterpret_cast<float4*>(p + tid * 8 + 4) = make_float4(x[4]*inv, x[5]*inv, x[6]*inv, x[7]*inv);
}

// ---------------------------------------------------------------------------
// Gate GEMV: logit = hidden[row,:512] . w2 + b2.  One wave per row.
// ---------------------------------------------------------------------------
__global__ __launch_bounds__(64)
void k_gate(const float* __restrict__ hidden, const float* __restrict__ w2,
            const float* __restrict__ b2,
            float* __restrict__ outLogit, float* __restrict__ outGate,
            float scl, float add)
{
    const long long row = blockIdx.x;
    const int lane = threadIdx.x;
    float s = 0.f;
#pragma unroll
    for (int j = 0; j < 8; ++j) {
        int idx = lane + j * 64;
        s += hidden[row * 512 + idx] * w2[idx];
    }
#pragma unroll
    for (int off = 32; off; off >>= 1) s += __shfl_xor(s, off);
    if (lane == 0) {
        float logit = s + b2[0];
        if (outLogit) outLogit[row] = logit;
        outGate[row] = sigmoidf_(logit * scl + add);
    }
}

// ---------------------------------------------------------------------------
// Slerp: one wave per row. a=prior_absolute, b=local. All fp32.
// ---------------------------------------------------------------------------
__global__ __launch_bounds__(64)
void k_slerp(const float* __restrict__ prior, const float* __restrict__ localv,
             const float* __restrict__ mixv, const float* __restrict__ anchor,
             float* __restrict__ cand, float* __restrict__ cdelta)
{
    const int row = blockIdx.x;
    const int lane = threadIdx.x;
    const long long base = (long long)row * 512 + lane * 8;
    const long long abase = (long long)(row >> 11) * 512 + lane * 8;

    float a[8], b[8];
    load8f(prior + base, a);
    load8f(localv + base, b);
    float sa = 0.f, sb = 0.f, sab = 0.f;
#pragma unroll
    for (int j = 0; j < 8; ++j) {
        sa = fmaf(a[j], a[j], sa); sb = fmaf(b[j], b[j], sb); sab = fmaf(a[j], b[j], sab);
    }
#pragma unroll
    for (int off = 1; off < 64; off <<= 1) {
        sa += __shfl_xor(sa, off); sb += __shfl_xor(sb, off); sab += __shfl_xor(sab, off);
    }
    const float eps = 1e-6f;
    float na = fmaxf(sqrtf(sa), eps), nb = fmaxf(sqrtf(sb), eps);
    float dot = sab / (na * nb);
    dot = fminf(fmaxf(dot, -1.f + eps), 1.f - eps);
    float omega = acosf(dot);
    float so = fmaxf(sinf(omega), eps);
    float t = mixv[row];
    t = fminf(fmaxf(t, 0.f), 1.f);
    float sca = sinf((1.f - t) * omega) / so;
    float scb = sinf(t * omega) / so;

    float an[8];
    load8f(anchor + abase, an);
    float c0[8], d0[8];
#pragma unroll
    for (int j = 0; j < 8; ++j) {
        c0[j] = sca * a[j] + scb * b[j];
        d0[j] = c0[j] - an[j];
    }
    *reinterpret_cast<float4*>(cand + base)       = make_float4(c0[0], c0[1], c0[2], c0[3]);
    *reinterpret_cast<float4*>(cand + base + 4)   = make_float4(c0[4], c0[5], c0[6], c0[7]);
    *reinterpret_cast<float4*>(cdelta + base)     = make_float4(d0[0], d0[1], d0[2], d0[3]);
    *reinterpret_cast<float4*>(cdelta + base + 4) = make_float4(d0[4], d0[5], d0[6], d0[7]);
}

// ---------------------------------------------------------------------------
extern "C" void kernel_launch(void* const* d_in, const int* in_sizes, int n_in,
                              void* d_out, int out_size, void* d_ws, size_t ws_size,
                              hipStream_t stream)
{
    const float* query  = (const float*)d_in[0];
    const float* anchor = (const float*)d_in[1];
    const float* gmem   = (const float*)d_in[2];
    const float* local_ = (const float*)d_in[3];
    const float* style  = (const float*)d_in[4];
    const float* Wq = (const float*)d_in[5];   const float* bq = (const float*)d_in[6];
    const float* Wk = (const float*)d_in[7];   const float* bk = (const float*)d_in[8];
    const float* Wv = (const float*)d_in[9];   const float* bv = (const float*)d_in[10];
    const float* Wo = (const float*)d_in[11];  const float* bo = (const float*)d_in[12];
    const float* Wm1 = (const float*)d_in[13]; const float* bm1 = (const float*)d_in[14];
    const float* Wm2 = (const float*)d_in[15]; const float* bm2 = (const float*)d_in[16];
    const float* Wg1 = (const float*)d_in[17]; const float* bg1 = (const float*)d_in[18];
    const float* Wg2 = (const float*)d_in[19]; const float* bg2 = (const float*)d_in[20];

    float* out = (float*)d_out;
    const long long SH = 16384LL * 512;          // B*S*H
    float* o_attn = out;                         // [B,S,M]
    float* o_pd   = out + 33554432LL;            // prior_delta
    float* o_pa   = o_pd + SH;                   // prior_absolute
    float* o_mix  = o_pa + SH;                   // mix [16384]
    float* o_ca   = o_mix + 16384;               // candidate_absolute
    float* o_cd   = o_ca + SH;                   // candidate_delta
    float* o_vl   = o_cd + SH;                   // variation_logit
    float* o_vg   = o_vl + 16384;                // variation_gate

    bf16* wq_  = (bf16*)d_ws;                    // q  [16384,512] bf16
    bf16* wk_  = wq_ + SH;                       // k
    bf16* wv_  = wk_ + SH;                       // v
    bf16* wctx = wv_ + SH;                       // attn@v
    float* whid = (float*)(wctx + SH);           // hidden [16384,512] f32

    const float invSqrtH = 0.04419417382415922f; // 1/sqrt(512)

    // q,k,v projections: [16384,512] x [512,512] -> bf16 ws
    k_mfma<0, 0, float, float><<<dim3(4, 128, 1), 256, 0, stream>>>(
        query, 0, 512, Wq, 0, 512, bq, wq_, 0, nullptr, nullptr, 512, 512, 1.f);
    k_mfma<0, 0, float, float><<<dim3(4, 128, 1), 256, 0, stream>>>(
        gmem, 0, 512, Wk, 0, 512, bk, wk_, 0, nullptr, nullptr, 512, 512, 1.f);
    k_mfma<0, 0, float, float><<<dim3(4, 128, 1), 256, 0, stream>>>(
        gmem, 0, 512, Wv, 0, 512, bv, wv_, 0, nullptr, nullptr, 512, 512, 1.f);
    // attention logits: q @ k^T per batch -> f32 d_out (scaled)
    k_mfma<1, 1, bf16, bf16><<<dim3(16, 16, 8), 256, 0, stream>>>(
        wq_, 2048LL * 512, 512, wk_, 2048LL * 512, 512, nullptr,
        o_attn, 2048LL * 2048, nullptr, nullptr, 2048, 512, invSqrtH);
    // softmax in-place (f32)
    k_softmax<<<16384, 256, 0, stream>>>(o_attn);
    // attn @ v -> ctx bf16 ws (A staged+converted from f32 d_out)
    k_mfma<0, 0, float, bf16><<<dim3(4, 16, 8), 256, 0, stream>>>(
        o_attn, 2048LL * 2048, 2048, wv_, 2048LL * 512, 512, nullptr,
        wctx, 2048LL * 512, nullptr, nullptr, 512, 2048, 1.f);
    // Wo projection + prior epilogue (pd, pa = pd + anchor)
    k_mfma<2, 0, bf16, float><<<dim3(4, 128, 1), 256, 0, stream>>>(
        wctx, 0, 512, Wo, 0, 512, bo, o_pd, 0, o_pa, anchor, 512, 512, 1.f);
    // mix gate MLP
    k_cat<<<dim3(4, 128, 1), 256, 0, stream>>>(query, o_pa, local_, style, 0, Wm1, bm1, whid);
    k_gate<<<16384, 64, 0, stream>>>(whid, Wm2, bm2, nullptr, o_mix, 1.0f, -0.25f);
    // slerp -> candidate_absolute, candidate_delta
    k_slerp<<<16384, 64, 0, stream>>>(o_pa, local_, o_mix, anchor, o_ca, o_cd);
    // variation gate MLP (src2 = anchor broadcast)
    k_cat<<<dim3(4, 128, 1), 256, 0, stream>>>(query, o_ca, anchor, style, 1, Wg1, bg1, whid);
    k_gate<<<16384, 64, 0, stream>>>(whid, Wg2, bg2, o_vl, o_vg, 1.0f, -1.0f);
}

// Round 4
// 508.388 us; speedup vs baseline: 6.3491x; 1.3121x over previous
//
#include <hip/hip_runtime.h>
#include <hip/hip_bf16.h>

typedef __hip_bfloat16 bf16;
typedef unsigned short u16;
typedef u16 u16x8 __attribute__((ext_vector_type(8)));
typedef u16 u16x4v __attribute__((ext_vector_type(4)));
typedef short bf16x8 __attribute__((ext_vector_type(8)));
typedef float f32x4 __attribute__((ext_vector_type(4)));

__device__ __forceinline__ float b2f(u16 u) {
    unsigned v = ((unsigned)u) << 16;
    float f; __builtin_memcpy(&f, &v, 4); return f;
}
__device__ __forceinline__ u16 f2u(float f) {
    bf16 h = __float2bfloat16(f);
    u16 u; __builtin_memcpy(&u, &h, 2); return u;
}
__device__ __forceinline__ float sigmoidf_(float x) { return 1.f / (1.f + expf(-x)); }
__device__ __forceinline__ void load8f(const float* __restrict__ p, float* x) {
    float4 a = *reinterpret_cast<const float4*>(p);
    float4 b = *reinterpret_cast<const float4*>(p + 4);
    x[0]=a.x; x[1]=a.y; x[2]=a.z; x[3]=a.w; x[4]=b.x; x[5]=b.y; x[6]=b.z; x[7]=b.w;
}

// async global->LDS, 16B per lane. LDS dest = wave-uniform base + lane*16.
__device__ __forceinline__ void gld16(const void* g, void* l) {
    typedef __attribute__((address_space(1))) const unsigned int GU;
    typedef __attribute__((address_space(3))) unsigned int LU;
    __builtin_amdgcn_global_load_lds((GU*)(unsigned long long)g,
                                     (LU*)(unsigned int)(unsigned long long)l, 16, 0, 0);
}

// ---------------------------------------------------------------------------
// m97-structure MFMA GEMM: C = A[m][k] . Bt[n][k]^T, batched over z.
// 128x128 tile, BK=32, 256 thr (4 waves 2x2), global_load_lds, linear LDS.
// EPI 0: bf16 outb (+bias), stride sO per z
// EPI 1: f32 out1 = acc*scale, stride sO per z
// EPI 2: Wo: out1=pd=acc+bias; out2=pa=pd+anchor; outb=bf16(pa)   (z=0)
// EPI 3: v_t: outb[(row>>11)*2048*512 + col*2048 + (row&2047)] = bf16(acc+bias)
// ---------------------------------------------------------------------------
template<int EPI>
__global__ __launch_bounds__(256)
void k_mfma(const bf16* __restrict__ A, long long sA, int lda,
            const bf16* __restrict__ Bt, long long sB, int ldb,
            const float* __restrict__ bias,
            bf16* __restrict__ outb, long long sO,
            float* __restrict__ out1, float* __restrict__ out2,
            const float* __restrict__ anchor,
            int N, int K, float scale)
{
    __shared__ short As[4096];
    __shared__ short Bs[4096];
    const int tid = threadIdx.x;
    const int z = blockIdx.z;
    const int n0 = blockIdx.x * 128, m0 = blockIdx.y * 128;
    const bf16* Az = A + (long long)z * sA;
    const bf16* Bz = Bt + (long long)z * sB;
    const int lrow = tid >> 2;          // 0..63 staging row
    const int lcol = (tid & 3) * 8;     // k-chunk within 32
    const int lane = tid & 63, w = tid >> 6;
    const int wm = (w >> 1) * 64, wn = (w & 1) * 64;
    const int fr = lane & 15, fq = lane >> 4;
    char* AsW = (char*)As + w * 1024;   // wave-uniform LDS staging base
    char* BsW = (char*)Bs + w * 1024;

    f32x4 acc[4][4];
#pragma unroll
    for (int i = 0; i < 4; ++i)
#pragma unroll
        for (int j = 0; j < 4; ++j) acc[i][j] = f32x4{0.f, 0.f, 0.f, 0.f};

    for (int k0 = 0; k0 < K; k0 += 32) {
        const bf16* ga = Az + (long long)(m0 + lrow) * lda + (k0 + lcol);
        const bf16* gb = Bz + (long long)(n0 + lrow) * ldb + (k0 + lcol);
        gld16(ga, AsW);
        gld16(ga + 64LL * lda, AsW + 4096);
        gld16(gb, BsW);
        gld16(gb + 64LL * ldb, BsW + 4096);
        __syncthreads();

        bf16x8 af[4], bfr[4];
#pragma unroll
        for (int i = 0; i < 4; ++i)
            af[i] = *reinterpret_cast<const bf16x8*>(&As[(wm + i * 16 + fr) * 32 + fq * 8]);
#pragma unroll
        for (int j = 0; j < 4; ++j)
            bfr[j] = *reinterpret_cast<const bf16x8*>(&Bs[(wn + j * 16 + fr) * 32 + fq * 8]);
#pragma unroll
        for (int i = 0; i < 4; ++i)
#pragma unroll
            for (int j = 0; j < 4; ++j)
                acc[i][j] = __builtin_amdgcn_mfma_f32_16x16x32_bf16(af[i], bfr[j], acc[i][j], 0, 0, 0);
        __syncthreads();
    }

#pragma unroll
    for (int j = 0; j < 4; ++j) {
        const int col = n0 + wn + j * 16 + fr;
        const float bv = bias ? bias[col] : 0.f;
#pragma unroll
        for (int i = 0; i < 4; ++i) {
#pragma unroll
            for (int r = 0; r < 4; ++r) {
                const long long row = m0 + wm + i * 16 + fq * 4 + r;
                const float v = acc[i][j][r];
                if constexpr (EPI == 0) {
                    outb[(long long)z * sO + row * N + col] = __float2bfloat16(v + bv);
                } else if constexpr (EPI == 1) {
                    out1[(long long)z * sO + row * N + col] = v * scale;
                } else if constexpr (EPI == 2) {
                    const float pd = v + bv;
                    const float pa = pd + anchor[(row >> 11) * 512 + col];
                    out1[row * N + col] = pd;
                    out2[row * N + col] = pa;
                    outb[row * N + col] = __float2bfloat16(pa);
                } else {
                    outb[(row >> 11) * 1048576LL + (long long)col * 2048 + (row & 2047)]
                        = __float2bfloat16(v + bv);
                }
            }
        }
    }
}

// ---------------------------------------------------------------------------
// Concat-gather MFMA GEMM (gate MLPs): A cols [0,2048) from 4 bf16 sources of
// 512 each (mode2=1: src2 = anchor_b[B,512] broadcast). Bt bf16 [512][2048].
// Epilogue: bf16 relu(acc+bias) -> whid_b.  M=16384, N=512, K=2048.
// ---------------------------------------------------------------------------
__global__ __launch_bounds__(256)
void k_cat(const bf16* __restrict__ s0b, const bf16* __restrict__ s1b,
           const bf16* __restrict__ s2b, const bf16* __restrict__ s3b,
           int mode2,
           const bf16* __restrict__ Bt, const float* __restrict__ bias,
           bf16* __restrict__ outb)
{
    __shared__ short As[4096];
    __shared__ short Bs[4096];
    const int tid = threadIdx.x;
    const int n0 = blockIdx.x * 128, m0 = blockIdx.y * 128;
    const int lrow = tid >> 2;
    const int lcol = (tid & 3) * 8;
    const int lane = tid & 63, w = tid >> 6;
    const int wm = (w >> 1) * 64, wn = (w & 1) * 64;
    const int fr = lane & 15, fq = lane >> 4;
    char* AsW = (char*)As + w * 1024;
    char* BsW = (char*)Bs + w * 1024;

    f32x4 acc[4][4];
#pragma unroll
    for (int i = 0; i < 4; ++i)
#pragma unroll
        for (int j = 0; j < 4; ++j) acc[i][j] = f32x4{0.f, 0.f, 0.f, 0.f};

    for (int k0 = 0; k0 < 2048; k0 += 32) {
        const int si = k0 >> 9;
        const bf16* sp = si == 0 ? s0b : si == 1 ? s1b : si == 2 ? s2b : s3b;
        const int kloc = (k0 & 511) + lcol;
        const int r = m0 + lrow;
        long long ro0, ro1;
        if (si == 2 && mode2) { ro0 = (long long)(r >> 11) * 512; ro1 = ro0; }
        else                  { ro0 = (long long)r * 512; ro1 = ro0 + 64LL * 512; }
        gld16(sp + ro0 + kloc, AsW);
        gld16(sp + ro1 + kloc, AsW + 4096);
        const bf16* gb = Bt + (long long)(n0 + lrow) * 2048 + (k0 + lcol);
        gld16(gb, BsW);
        gld16(gb + 64LL * 2048, BsW + 4096);
        __syncthreads();

        bf16x8 af[4], bfr[4];
#pragma unroll
        for (int i = 0; i < 4; ++i)
            af[i] = *reinterpret_cast<const bf16x8*>(&As[(wm + i * 16 + fr) * 32 + fq * 8]);
#pragma unroll
        for (int j = 0; j < 4; ++j)
            bfr[j] = *reinterpret_cast<const bf16x8*>(&Bs[(wn + j * 16 + fr) * 32 + fq * 8]);
#pragma unroll
        for (int i = 0; i < 4; ++i)
#pragma unroll
            for (int j = 0; j < 4; ++j)
                acc[i][j] = __builtin_amdgcn_mfma_f32_16x16x32_bf16(af[i], bfr[j], acc[i][j], 0, 0, 0);
        __syncthreads();
    }

#pragma unroll
    for (int j = 0; j < 4; ++j) {
        const int col = n0 + wn + j * 16 + fr;
        const float bv = bias[col];
#pragma unroll
        for (int i = 0; i < 4; ++i)
#pragma unroll
            for (int r = 0; r < 4; ++r) {
                const long long row = m0 + wm + i * 16 + fq * 4 + r;
                outb[row * 512 + col] = __float2bfloat16(fmaxf(acc[i][j][r] + bv, 0.f));
            }
    }
}

// ---------------------------------------------------------------------------
// f32 -> bf16 elementwise convert, 8/thread. n multiple of 2048.
// ---------------------------------------------------------------------------
__global__ __launch_bounds__(256)
void k_cvt(const float* __restrict__ s, bf16* __restrict__ d, int n)
{
    long long i = ((long long)blockIdx.x * 256 + threadIdx.x) * 8;
    if (i >= n) return;
    float x[8]; load8f(s + i, x);
    u16x8 o;
#pragma unroll
    for (int j = 0; j < 8; ++j) o[j] = f2u(x[j]);
    *reinterpret_cast<u16x8*>(d + i) = o;
}

// ---------------------------------------------------------------------------
// Transposing convert: src f32 [R][C] -> dst bf16 [C][R]. 32x32 tiles.
// Up to 4 matrices per launch via blockIdx.z.
// ---------------------------------------------------------------------------
__global__ __launch_bounds__(256)
void k_tr(const float* s0, bf16* d0, const float* s1, bf16* d1,
          const float* s2, bf16* d2, const float* s3, bf16* d3,
          int R, int C)
{
    __shared__ float t[32][33];
    const int zz = blockIdx.z;
    const float* s = zz == 0 ? s0 : zz == 1 ? s1 : zz == 2 ? s2 : s3;
    bf16* d = zz == 0 ? d0 : zz == 1 ? d1 : zz == 2 ? d2 : d3;
    const int c0 = blockIdx.x * 32, r0 = blockIdx.y * 32;
    const int tr = threadIdx.x >> 3, tc = (threadIdx.x & 7) * 4;
    float4 v = *reinterpret_cast<const float4*>(s + (long long)(r0 + tr) * C + c0 + tc);
    t[tr][tc] = v.x; t[tr][tc + 1] = v.y; t[tr][tc + 2] = v.z; t[tr][tc + 3] = v.w;
    __syncthreads();
    u16x4v o;
    o[0] = f2u(t[tc + 0][tr]); o[1] = f2u(t[tc + 1][tr]);
    o[2] = f2u(t[tc + 2][tr]); o[3] = f2u(t[tc + 3][tr]);
    *reinterpret_cast<u16x4v*>(d + (long long)(c0 + tr) * R + r0 + tc) = o;
}

// ---------------------------------------------------------------------------
// In-place row softmax over rows of 2048 f32; also emits bf16 copy of P.
// ---------------------------------------------------------------------------
__global__ __launch_bounds__(256)
void k_softmax(float* __restrict__ attn, bf16* __restrict__ pb)
{
    __shared__ float redm[4], reds[4];
    const long long row = blockIdx.x;
    float* p = attn + row * 2048;
    const int tid = threadIdx.x;

    float x[8];
    load8f(p + tid * 8, x);
    float mx = -1e30f;
#pragma unroll
    for (int j = 0; j < 8; ++j) mx = fmaxf(mx, x[j]);
#pragma unroll
    for (int off = 32; off; off >>= 1) mx = fmaxf(mx, __shfl_xor(mx, off));
    if ((tid & 63) == 0) redm[tid >> 6] = mx;
    __syncthreads();
    mx = fmaxf(fmaxf(redm[0], redm[1]), fmaxf(redm[2], redm[3]));

    float s = 0.f;
#pragma unroll
    for (int j = 0; j < 8; ++j) { x[j] = expf(x[j] - mx); s += x[j]; }
#pragma unroll
    for (int off = 32; off; off >>= 1) s += __shfl_xor(s, off);
    if ((tid & 63) == 0) reds[tid >> 6] = s;
    __syncthreads();
    const float inv = 1.f / (reds[0] + reds[1] + reds[2] + reds[3]);

    u16x8 ob;
#pragma unroll
    for (int j = 0; j < 8; ++j) { x[j] *= inv; ob[j] = f2u(x[j]); }
    *reinterpret_cast<float4*>(p + tid * 8)     = make_float4(x[0], x[1], x[2], x[3]);
    *reinterpret_cast<float4*>(p + tid * 8 + 4) = make_float4(x[4], x[5], x[6], x[7]);
    *reinterpret_cast<u16x8*>(pb + row * 2048 + tid * 8) = ob;
}

// ---------------------------------------------------------------------------
// Gate GEMV over bf16 hidden: logit = hidden[row,:512] . w2 + b2. One wave/row.
// ---------------------------------------------------------------------------
__global__ __launch_bounds__(64)
void k_gate(const bf16* __restrict__ hidden, const float* __restrict__ w2,
            const float* __restrict__ b2,
            float* __restrict__ outLogit, float* __restrict__ outGate,
            float scl, float add)
{
    const long long row = blockIdx.x;
    const int lane = threadIdx.x;
    u16x8 u = *reinterpret_cast<const u16x8*>(hidden + row * 512 + lane * 8);
    float wv[8];
    load8f(w2 + lane * 8, wv);
    float s = 0.f;
#pragma unroll
    for (int j = 0; j < 8; ++j) s = fmaf(b2f(u[j]), wv[j], s);
#pragma unroll
    for (int off = 32; off; off >>= 1) s += __shfl_xor(s, off);
    if (lane == 0) {
        float logit = s + b2[0];
        if (outLogit) outLogit[row] = logit;
        outGate[row] = sigmoidf_(logit * scl + add);
    }
}

// ---------------------------------------------------------------------------
// Slerp: one wave per row. a=prior_absolute(f32), b=local(f32). Emits f32
// cand/cdelta + bf16 cand copy for the var-MLP.
// ---------------------------------------------------------------------------
__global__ __launch_bounds__(64)
void k_slerp(const float* __restrict__ prior, const float* __restrict__ localv,
             const float* __restrict__ mixv, const float* __restrict__ anchor,
             float* __restrict__ cand, float* __restrict__ cdelta,
             bf16* __restrict__ candb)
{
    const int row = blockIdx.x;
    const int lane = threadIdx.x;
    const long long base = (long long)row * 512 + lane * 8;
    const long long abase = (long long)(row >> 11) * 512 + lane * 8;

    float a[8], b[8];
    load8f(prior + base, a);
    load8f(localv + base, b);
    float sa = 0.f, sb = 0.f, sab = 0.f;
#pragma unroll
    for (int j = 0; j < 8; ++j) {
        sa = fmaf(a[j], a[j], sa); sb = fmaf(b[j], b[j], sb); sab = fmaf(a[j], b[j], sab);
    }
#pragma unroll
    for (int off = 1; off < 64; off <<= 1) {
        sa += __shfl_xor(sa, off); sb += __shfl_xor(sb, off); sab += __shfl_xor(sab, off);
    }
    const float eps = 1e-6f;
    float na = fmaxf(sqrtf(sa), eps), nb = fmaxf(sqrtf(sb), eps);
    float dot = sab / (na * nb);
    dot = fminf(fmaxf(dot, -1.f + eps), 1.f - eps);
    float omega = acosf(dot);
    float so = fmaxf(sinf(omega), eps);
    float t = mixv[row];
    t = fminf(fmaxf(t, 0.f), 1.f);
    float sca = sinf((1.f - t) * omega) / so;
    float scb = sinf(t * omega) / so;

    float an[8];
    load8f(anchor + abase, an);
    float c0[8], d0[8];
    u16x8 cb;
#pragma unroll
    for (int j = 0; j < 8; ++j) {
        c0[j] = sca * a[j] + scb * b[j];
        d0[j] = c0[j] - an[j];
        cb[j] = f2u(c0[j]);
    }
    *reinterpret_cast<float4*>(cand + base)       = make_float4(c0[0], c0[1], c0[2], c0[3]);
    *reinterpret_cast<float4*>(cand + base + 4)   = make_float4(c0[4], c0[5], c0[6], c0[7]);
    *reinterpret_cast<float4*>(cdelta + base)     = make_float4(d0[0], d0[1], d0[2], d0[3]);
    *reinterpret_cast<float4*>(cdelta + base + 4) = make_float4(d0[4], d0[5], d0[6], d0[7]);
    *reinterpret_cast<u16x8*>(candb + base) = cb;
}

// ---------------------------------------------------------------------------
extern "C" void kernel_launch(void* const* d_in, const int* in_sizes, int n_in,
                              void* d_out, int out_size, void* d_ws, size_t ws_size,
                              hipStream_t stream)
{
    const float* query  = (const float*)d_in[0];
    const float* anchor = (const float*)d_in[1];
    const float* gmem   = (const float*)d_in[2];
    const float* local_ = (const float*)d_in[3];
    const float* style  = (const float*)d_in[4];
    const float* Wq = (const float*)d_in[5];   const float* bq = (const float*)d_in[6];
    const float* Wk = (const float*)d_in[7];   const float* bk = (const float*)d_in[8];
    const float* Wv = (const float*)d_in[9];   const float* bv = (const float*)d_in[10];
    const float* Wo = (const float*)d_in[11];  const float* bo = (const float*)d_in[12];
    const float* Wm1 = (const float*)d_in[13]; const float* bm1 = (const float*)d_in[14];
    const float* Wm2 = (const float*)d_in[15]; const float* bm2 = (const float*)d_in[16];
    const float* Wg1 = (const float*)d_in[17]; const float* bg1 = (const float*)d_in[18];
    const float* Wg2 = (const float*)d_in[19]; const float* bg2 = (const float*)d_in[20];

    float* out = (float*)d_out;
    const long long SHE = 8388608LL;             // B*S*H elems
    float* o_attn = out;                         // [B,S,M]
    float* o_pd   = out + 33554432LL;            // prior_delta
    float* o_pa   = o_pd + SHE;                  // prior_absolute
    float* o_mix  = o_pa + SHE;                  // mix [16384]
    float* o_ca   = o_mix + 16384;               // candidate_absolute
    float* o_cd   = o_ca + SHE;                  // candidate_delta
    float* o_vl   = o_cd + SHE;                  // variation_logit
    float* o_vg   = o_vl + 16384;                // variation_gate

    // ws slots (bf16, 8.4M elems each, aggressively reused):
    bf16* S0q = (bf16*)d_ws;       // query_b (whole run)
    bf16* S1  = S0q + SHE;         // gmem_b -> ctx_b -> whid_b
    bf16* S2  = S1 + SHE;          // q_b -> pa_b -> ca_b
    bf16* S3  = S2 + SHE;          // k_b -> local_b
    bf16* S4  = S3 + SHE;          // v_t -> style_b
    bf16* wtq = S4 + SHE;          // transposed weights (bf16)
    bf16* wtk = wtq + 262144;
    bf16* wtv = wtk + 262144;
    bf16* wto = wtv + 262144;
    bf16* wtm1 = wto + 262144;     // [512][2048]
    bf16* wtg1 = wtm1 + 1048576;   // [512][2048]
    bf16* anb  = wtg1 + 1048576;   // anchor_b [8,512]
    bf16* p_b  = (bf16*)o_ca;      // bf16 P scratch in not-yet-written d_out (67 MB)

    const float invSqrtH = 0.04419417382415922f; // 1/sqrt(512)

    // prologue: bf16 conversions + weight transposes
    k_cvt<<<4096, 256, 0, stream>>>(query, S0q, 8388608);
    k_cvt<<<4096, 256, 0, stream>>>(gmem, S1, 8388608);
    k_cvt<<<2, 256, 0, stream>>>(anchor, anb, 4096);
    k_tr<<<dim3(16, 16, 4), 256, 0, stream>>>(Wq, wtq, Wk, wtk, Wv, wtv, Wo, wto, 512, 512);
    k_tr<<<dim3(16, 64, 2), 256, 0, stream>>>(Wm1, wtm1, Wg1, wtg1,
                                              nullptr, nullptr, nullptr, nullptr, 2048, 512);
    // q,k,v projections (v written transposed per batch)
    k_mfma<0><<<dim3(4, 128, 1), 256, 0, stream>>>(S0q, 0, 512, wtq, 0, 512, bq,
        S2, 0, nullptr, nullptr, nullptr, 512, 512, 1.f);
    k_mfma<0><<<dim3(4, 128, 1), 256, 0, stream>>>(S1, 0, 512, wtk, 0, 512, bk,
        S3, 0, nullptr, nullptr, nullptr, 512, 512, 1.f);
    k_mfma<3><<<dim3(4, 128, 1), 256, 0, stream>>>(S1, 0, 512, wtv, 0, 512, bv,
        S4, 0, nullptr, nullptr, nullptr, 512, 512, 1.f);
    // attention logits (NT): q_b . k_b^T * scale -> f32 o_attn
    k_mfma<1><<<dim3(16, 16, 8), 256, 0, stream>>>(S2, 2048LL * 512, 512, S3, 2048LL * 512, 512,
        nullptr, nullptr, 4194304LL, o_attn, nullptr, nullptr, 2048, 512, invSqrtH);
    // softmax in place + bf16 P copy
    k_softmax<<<16384, 256, 0, stream>>>(o_attn, p_b);
    // PV: P_b . v_t^T -> ctx_b (S1; gmem_b dead)
    k_mfma<0><<<dim3(4, 16, 8), 256, 0, stream>>>(p_b, 4194304LL, 2048, S4, 1048576LL, 2048,
        nullptr, S1, 1048576LL, nullptr, nullptr, nullptr, 512, 2048, 1.f);
    // free slots S3/S4 after QK^T/PV -> convert local/style
    k_cvt<<<4096, 256, 0, stream>>>(local_, S3, 8388608);
    k_cvt<<<4096, 256, 0, stream>>>(style, S4, 8388608);
    // Wo projection + prior epilogue (pd, pa, pa_b -> S2)
    k_mfma<2><<<dim3(4, 128, 1), 256, 0, stream>>>(S1, 0, 512, wto, 0, 512, bo,
        S2, 0, o_pd, o_pa, anchor, 512, 512, 1.f);
    // mix gate MLP (whid_b -> S1; ctx_b dead)
    k_cat<<<dim3(4, 128, 1), 256, 0, stream>>>(S0q, S2, S3, S4, 0, wtm1, bm1, S1);
    k_gate<<<16384, 64, 0, stream>>>(S1, Wm2, bm2, nullptr, o_mix, 1.0f, -0.25f);
    // slerp -> candidate_absolute/delta (+ca_b -> S2; pa_b dead)
    k_slerp<<<16384, 64, 0, stream>>>(o_pa, local_, o_mix, anchor, o_ca, o_cd, S2);
    // variation gate MLP (src2 = anchor_b broadcast)
    k_cat<<<dim3(4, 128, 1), 256, 0, stream>>>(S0q, S2, anb, S4, 1, wtg1, bg1, S1);
    k_gate<<<16384, 64, 0, stream>>>(S1, Wg2, bg2, o_vl, o_vg, 1.0f, -1.0f);
}